// Round 5
// baseline (27.397 us; speedup 1.0000x reference)
//
#include <hip/hip_runtime.h>
#include <math.h>

typedef __attribute__((ext_vector_type(8)))  short short8v;
typedef __attribute__((ext_vector_type(16))) float f32x16;

#define BLOCK 256
#define WPB   4
// rows per wave = 64; grid sized so waves*64 == nB (grid-stride for safety)

__device__ inline unsigned int pk_bf16(float lo, float hi) {
    unsigned int r;
    asm("v_cvt_pk_bf16_f32 %0, %1, %2" : "=v"(r) : "v"(lo), "v"(hi));
    return r;
}
__device__ inline short8v as_s8(uint4 v) { union { uint4 u; short8v s; } c; c.u = v; return c.s; }
union F4 { float4 v; float f[4]; };

__global__ __launch_bounds__(BLOCK) void bnet(
    const float* __restrict__ x,
    const float* __restrict__ meanp, const float* __restrict__ stdp,
    const float* __restrict__ W1,  const float* __restrict__ b1,
    const float* __restrict__ W21, const float* __restrict__ b21,
    const float* __restrict__ W22, const float* __restrict__ b22,
    const float* __restrict__ W31, const float* __restrict__ b31,
    const float* __restrict__ W32, const float* __restrict__ b32,
    const float* __restrict__ obstacles,
    float* __restrict__ out, int nB)
{
    // Layer-2 A-fragments (32x32x16, swapped): A[m=unit_out][k], K=128 over
    // h-units in permuted order pi: k=16ks+8hi+j -> u = 32g+8d+4hi+c with
    // g=ks>>1, d=2(ks&1)+(j>>2), c=j&3. Lane slot: uo=lane&31, hi=lane>>5.
    // XOR-permuted lane slot kills the 8-way b128 bank conflict.
    __shared__ uint4 fragA2[2 * 8 * 64];   // 16 KB

    const int t = threadIdx.x;

    {   // stage W2 fragments -> LDS (per block, cooperative)
        #pragma unroll
        for (int i = 0; i < 4; ++i) {
            int e   = t + 256 * i;
            int mat = e >> 9, ks = (e >> 6) & 7, ln = e & 63;
            int uo  = ln & 31, lhi = ln >> 5;
            const float* w2  = mat ? W22 : W21;
            const float* src = w2 + uo * 128 + 16 * ks + 4 * lhi;
            float4 f0 = *(const float4*)src;
            float4 f1 = *(const float4*)(src + 8);
            uint4 v;
            v.x = pk_bf16(f0.x, f0.y); v.y = pk_bf16(f0.z, f0.w);
            v.z = pk_bf16(f1.x, f1.y); v.w = pk_bf16(f1.z, f1.w);
            int perm = (ln ^ (ln >> 3)) & 63;            // bank-spread
            fragA2[(mat * 8 + ks) * 64 + perm] = v;
        }
    }

    const int lane = t & 63;
    const int l31  = lane & 31;
    const int hi   = lane >> 5;
    const int wid  = blockIdx.x * WPB + (t >> 6);
    const int nw   = gridDim.x * WPB;

    // ---- W1 A-fragments, built directly from global (no LDS) ----
    // A[m=unit][k]: unit = 32g + l31; k=0..4 weights, k=5 bias, k>=8 (hi=1) zero.
    short8v w1a[4];
    #pragma unroll
    for (int g = 0; g < 4; ++g) {
        const float* wr = W1 + (32 * g + l31) * 5;
        float bb = b1[32 * g + l31];
        uint4 v;
        v.x = hi ? 0u : pk_bf16(wr[0], wr[1]);
        v.y = hi ? 0u : pk_bf16(wr[2], wr[3]);
        v.z = hi ? 0u : pk_bf16(wr[4], bb);
        v.w = 0u;
        w1a[g] = as_s8(v);
    }

    // ---- head coefficients / biases, resident per lane (its 16 units) ----
    // unit(reg=4d+c, hi) = c + 8d + 4hi  -> float4 at offset 8d+4hi.
    F4 cb21[4], cb22[4], c310[4], c311[4], c320[4], c321[4];
    #pragma unroll
    for (int d = 0; d < 4; ++d) {
        int o = 8 * d + 4 * hi;
        cb21[d].v = *(const float4*)(b21 + o);
        cb22[d].v = *(const float4*)(b22 + o);
        c310[d].v = *(const float4*)(W31 + o);
        c311[d].v = *(const float4*)(W31 + 32 + o);
        c320[d].v = *(const float4*)(W32 + o);
        c321[d].v = *(const float4*)(W32 + 32 + o);
    }
    const float b31_0 = b31[0], b31_1 = b31[1];
    const float b32_0 = b32[0], b32_1 = b32[1];

    // xo = (x*std+mean)*std+mean = x*std^2 + (mean*std+mean)
    float s2[5], ms[5];
    #pragma unroll
    for (int c = 0; c < 5; ++c) { float m = meanp[c], s = stdp[c]; s2[c] = s * s; ms[c] = fmaf(m, s, m); }

    // obstacles (broadcast, resident)
    float obx[8], oby[8], obr2[8];
    #pragma unroll
    for (int j = 0; j < 8; ++j) {
        obx[j] = obstacles[j * 3];
        oby[j] = obstacles[j * 3 + 1];
        float rr = obstacles[j * 3 + 2];
        obr2[j] = rr * rr;
    }

    __syncthreads();

    // ---- W2 fragments -> registers ----
    short8v a21f[8], a22f[8];
    {
        int perm = (lane ^ (lane >> 3)) & 63;
        #pragma unroll
        for (int ks = 0; ks < 8; ++ks) {
            a21f[ks] = as_s8(fragA2[(0 + ks) * 64 + perm]);
            a22f[ks] = as_s8(fragA2[(8 + ks) * 64 + perm]);
        }
    }

    const int nmac = (nB + 63) >> 6;
    for (int mac = wid; mac < nmac; mac += nw) {
        const int mbase = mac << 6;
        const int myrow = mbase + lane;
        const int rl = (myrow < nB) ? myrow : (nB - 1);

        float xe[5];
        {
            const float* xp = x + (size_t)rl * 5;
            #pragma unroll
            for (int c = 0; c < 5; ++c) xe[c] = xp[c];
        }

        float hx0 = 0.f, hx1 = 0.f, ht0 = 0.f, ht1 = 0.f;   // selected heads

        #pragma unroll
        for (int b = 0; b < 2; ++b) {
            // x B-fragment for block b: n=row=l31 (of block), k=8hi+j:
            // hi=0: {x0..x4, 1.0}; hi=1: zeros.
            float xb0 = __shfl(xe[0], 32 * b + l31);
            float xb1 = __shfl(xe[1], 32 * b + l31);
            float xb2 = __shfl(xe[2], 32 * b + l31);
            float xb3 = __shfl(xe[3], 32 * b + l31);
            float xb4 = __shfl(xe[4], 32 * b + l31);
            uint4 xv;
            xv.x = hi ? 0u : pk_bf16(xb0, xb1);
            xv.y = hi ? 0u : pk_bf16(xb2, xb3);
            xv.z = hi ? 0u : pk_bf16(xb4, 1.0f);
            xv.w = 0u;
            short8v xf = as_s8(xv);

            // layer 1: 4 MFMA, units 32g..32g+31 x 32 rows
            f32x16 ha0, ha1, ha2, ha3;
            {
                f32x16 z = {};
                ha0 = __builtin_amdgcn_mfma_f32_32x32x16_bf16(w1a[0], xf, z, 0, 0, 0);
                ha1 = __builtin_amdgcn_mfma_f32_32x32x16_bf16(w1a[1], xf, z, 0, 0, 0);
                ha2 = __builtin_amdgcn_mfma_f32_32x32x16_bf16(w1a[2], xf, z, 0, 0, 0);
                ha3 = __builtin_amdgcn_mfma_f32_32x32x16_bf16(w1a[3], xf, z, 0, 0, 0);
            }

            // relu + pack into layer-2 B-fragments: frag ks slot j = reg 8(ks&1)+j
            // of ha[g=ks>>1]  (register-local by construction of pi)
            short8v af[8];
            #pragma unroll
            for (int ks = 0; ks < 8; ++ks) {
                const int kk = 8 * (ks & 1);
                f32x16 hg = (ks >> 1) == 0 ? ha0 : (ks >> 1) == 1 ? ha1 : (ks >> 1) == 2 ? ha2 : ha3;
                uint4 v;
                v.x = pk_bf16(fmaxf(hg[kk + 0], 0.f), fmaxf(hg[kk + 1], 0.f));
                v.y = pk_bf16(fmaxf(hg[kk + 2], 0.f), fmaxf(hg[kk + 3], 0.f));
                v.z = pk_bf16(fmaxf(hg[kk + 4], 0.f), fmaxf(hg[kk + 5], 0.f));
                v.w = pk_bf16(fmaxf(hg[kk + 6], 0.f), fmaxf(hg[kk + 7], 0.f));
                af[ks] = as_s8(v);
            }

            // layer 2: 16 MFMA (2 chains of 8)
            f32x16 acc21 = {}, acc22 = {};
            #pragma unroll
            for (int ks = 0; ks < 8; ++ks) {
                acc21 = __builtin_amdgcn_mfma_f32_32x32x16_bf16(a21f[ks], af[ks], acc21, 0, 0, 0);
                acc22 = __builtin_amdgcn_mfma_f32_32x32x16_bf16(a22f[ks], af[ks], acc22, 0, 0, 0);
            }

            // heads: per-lane dot over its 16 units, + partner lane (xor 32)
            float p0 = 0.f, p1 = 0.f, p2 = 0.f, p3 = 0.f;
            #pragma unroll
            for (int d = 0; d < 4; ++d) {
                #pragma unroll
                for (int c = 0; c < 4; ++c) {
                    float v21 = fmaxf(acc21[4 * d + c] + cb21[d].f[c], 0.f);
                    float v22 = fmaxf(acc22[4 * d + c] + cb22[d].f[c], 0.f);
                    p0 = fmaf(v21, c310[d].f[c], p0);
                    p1 = fmaf(v21, c311[d].f[c], p1);
                    p2 = fmaf(v22, c320[d].f[c], p2);
                    p3 = fmaf(v22, c321[d].f[c], p3);
                }
            }
            p0 += __shfl_xor(p0, 32);
            p1 += __shfl_xor(p1, 32);
            p2 += __shfl_xor(p2, 32);
            p3 += __shfl_xor(p3, 32);

            // keep the block that owns this lane's row (hi == b)
            if (hi == b) { hx0 = p0; hx1 = p1; ht0 = p2; ht1 = p3; }
        }

        // ---- per-lane epilogue: row = mbase + lane (1:1, no redundancy) ----
        float x31_0 = hx0 + b31_0;
        float x31_1 = hx1 + b31_1;
        float t32_0 = ht0 + b32_0;
        float t32_1 = ht1 + b32_1;

        float s0v = __fdividef(4.f, 1.f + __expf(-t32_0));
        float s1v = __fdividef(4.f, 1.f + __expf(-t32_1));
        float hcoef = s0v * s1v;

        float xo[5];
        #pragma unroll
        for (int c = 0; c < 5; ++c) xo[c] = fmaf(xe[c], s2[c], ms[c]);
        float px = xo[0], py = xo[1], th = xo[2], oppx = xo[3], oppy = xo[4];
        float st, ct;
        __sincosf(th, &st, &ct);

        float upper = INFINITY, lower = -INFINITY;
        #pragma unroll
        for (int j = 0; j < 9; ++j) {
            float ox  = (j < 8) ? obx[j]  : oppx;
            float oy  = (j < 8) ? oby[j]  : oppy;
            float rr2 = (j < 8) ? obr2[j] : (0.3f * 0.3f);
            float dx = px - ox, dy = py - oy;
            float bar = fmaf(dx, dx, fmaf(dy, dy, -rr2));
            float g1  = -2.f * fmaf(dx, ct, dy * st);
            float ratio = __fdividef(hcoef * bar, (g1 != 0.f) ? g1 : 1.f);
            if (g1 > 0.f) upper = fminf(upper, ratio);
            if (g1 < 0.f) lower = fmaxf(lower, ratio);
        }
        float u1 = fminf(fmaxf(-x31_0, lower), upper);
        float u2 = -x31_1;

        if (myrow < nB) {
            float2 o; o.x = u1; o.y = u2;
            *reinterpret_cast<float2*>(out + 2 * (size_t)myrow) = o;
        }
    }
}

extern "C" void kernel_launch(void* const* d_in, const int* in_sizes, int n_in,
                              void* d_out, int out_size, void* d_ws, size_t ws_size,
                              hipStream_t stream) {
    const float* x         = (const float*)d_in[0];
    const float* meanp     = (const float*)d_in[1];
    const float* stdp      = (const float*)d_in[2];
    const float* W1        = (const float*)d_in[3];
    const float* b1        = (const float*)d_in[4];
    const float* W21       = (const float*)d_in[5];
    const float* b21       = (const float*)d_in[6];
    const float* W22       = (const float*)d_in[7];
    const float* b22       = (const float*)d_in[8];
    const float* W31       = (const float*)d_in[9];
    const float* b31       = (const float*)d_in[10];
    const float* W32       = (const float*)d_in[11];
    const float* b32       = (const float*)d_in[12];
    const float* obstacles = (const float*)d_in[13];
    float* out = (float*)d_out;

    int nB = in_sizes[0] / 5;
    int rowsPerBlock = 64 * WPB;                       // 256 rows/block
    int grid = (nB + rowsPerBlock - 1) / rowsPerBlock; // 1024 for B=262144
    bnet<<<grid, BLOCK, 0, stream>>>(
        x, meanp, stdp, W1, b1, W21, b21, W22, b22,
        W31, b31, W32, b32, obstacles, out, nB);
}

// Round 6
// 27.127 us; speedup vs baseline: 1.0100x; 1.0100x over previous
//
#include <hip/hip_runtime.h>
#include <math.h>

typedef __attribute__((ext_vector_type(8))) short short8v;
typedef __attribute__((ext_vector_type(4))) float f32x4;

#define BLOCK 256
#define WPB   4
#define GRID  1024

__device__ inline unsigned int pk_bf16(float lo, float hi) {
    unsigned int r;
    asm("v_cvt_pk_bf16_f32 %0, %1, %2" : "=v"(r) : "v"(lo), "v"(hi));
    return r;
}
__device__ inline short8v as_s8(uint4 v) { union { uint4 u; short8v s; } c; c.u = v; return c.s; }
__device__ inline f32x4 as_f4(float4 v) { union { float4 u; f32x4 s; } c; c.u = v; return c.s; }

__global__ __launch_bounds__(BLOCK, 4) void bnet(
    const float* __restrict__ x,
    const float* __restrict__ meanp, const float* __restrict__ stdp,
    const float* __restrict__ W1,  const float* __restrict__ b1,
    const float* __restrict__ W21, const float* __restrict__ b21,
    const float* __restrict__ W22, const float* __restrict__ b22,
    const float* __restrict__ W31, const float* __restrict__ b31,
    const float* __restrict__ W32, const float* __restrict__ b32,
    const float* __restrict__ obstacles,
    float* __restrict__ out, int nB)
{
    // Layer-1 A-frags: [g*64+lane]; lanes<16 hold W1 row 16g+m (k=0..4 w, k=5 b1).
    __shared__ uint4 w1frag[8 * 64];                  // 8 KB
    // Layer-2 A-frags with pi-permuted K (verified in round 4).
    __shared__ uint4 fragB[16 * 64];                  // 16 KB
    // Head A-frags: m=0..1 -> W31 rows (k<32, sigma-perm), m=2..3 -> W32 (k>=32).
    __shared__ uint4 headA[2 * 64];                   // 2 KB
    __shared__ __align__(16) float b2s[64];           // b21[32] | b22[32]

    const int t = threadIdx.x;

    {   // zero w1frag (lanes >=16 must be zero)
        uint4 z = {0u, 0u, 0u, 0u};
        w1frag[t] = z; w1frag[t + 256] = z;
    }
    __syncthreads();
    if (t < 128) {   // W1 fragments
        int m = t & 15, g = t >> 4;
        int u = 16 * g + m;
        const float* wr = W1 + u * 5;
        uint4 v;
        v.x = pk_bf16(wr[0], wr[1]);
        v.y = pk_bf16(wr[2], wr[3]);
        v.z = pk_bf16(wr[4], b1[u]);
        v.w = 0u;
        w1frag[g * 64 + m] = v;
    } else {         // head A-fragments (threads 128..255)
        int e  = t - 128;
        int ks = e >> 6, l = e & 63, m = l & 15, qq = l >> 4;
        float v[8];
        #pragma unroll
        for (int j = 0; j < 8; ++j) {
            int u = 16 * ((j >> 2) & 1) + 4 * qq + (j & 3);   // sigma^-1
            float val = 0.f;
            if (m == 0 && ks == 0) val = W31[u];
            if (m == 1 && ks == 0) val = W31[32 + u];
            if (m == 2 && ks == 1) val = W32[u];
            if (m == 3 && ks == 1) val = W32[32 + u];
            v[j] = val;
        }
        uint4 h;
        h.x = pk_bf16(v[0], v[1]); h.y = pk_bf16(v[2], v[3]);
        h.z = pk_bf16(v[4], v[5]); h.w = pk_bf16(v[6], v[7]);
        headA[ks * 64 + l] = h;
    }
    if (t < 64) b2s[t] = (t < 32) ? b21[t] : b22[t - 32];
    {   // layer-2 fragments (identical mapping to round 4 - verified)
        const float4* w21v = (const float4*)W21;
        const float4* w22v = (const float4*)W22;
        #pragma unroll
        for (int e = 0; e < 4; ++e) {
            int g4   = t + e * 256;
            int uo   = g4 >> 5;
            int h0   = (g4 & 31) << 2;
            int ks   = h0 >> 5;
            int jh   = (h0 >> 4) & 1;
            int qq   = (h0 >> 2) & 3;
            int ln   = (qq << 4) | (uo & 15);
            int half = uo >> 4;
            float4 f1 = w21v[g4];
            float4 f2 = w22v[g4];
            unsigned int* dA = (unsigned int*)&fragB[(half * 4 + ks) * 64 + ln];
            unsigned int* dB = (unsigned int*)&fragB[(8 + half * 4 + ks) * 64 + ln];
            dA[jh * 2] = pk_bf16(f1.x, f1.y); dA[jh * 2 + 1] = pk_bf16(f1.z, f1.w);
            dB[jh * 2] = pk_bf16(f2.x, f2.y); dB[jh * 2 + 1] = pk_bf16(f2.z, f2.w);
        }
    }
    __syncthreads();

    const int lane = t & 63;
    const int q    = lane >> 4;
    const bool h16 = (lane < 16);
    const int wid    = blockIdx.x * WPB + (t >> 6);
    const int nwaves = GRID * WPB;

    // Resident: W2 fragments (64 VGPR) + head A-frags (8 VGPR).
    short8v bfr[16];
    #pragma unroll
    for (int i = 0; i < 16; ++i) bfr[i] = as_s8(fragB[i * 64 + lane]);
    const short8v hA0 = as_s8(headA[lane]);
    const short8v hA1 = as_s8(headA[64 + lane]);

    // Uniform scalars (SGPR-resident).
    const float hb0 = b31[0], hb1 = b31[1], hb2 = b32[0], hb3 = b32[1];
    float s2[5], ms[5];
    #pragma unroll
    for (int c = 0; c < 5; ++c) { float m = meanp[c], s = stdp[c]; s2[c] = s * s; ms[c] = fmaf(m, s, m); }
    float obx[8], oby[8], obr2[8];
    #pragma unroll
    for (int j = 0; j < 8; ++j) {
        obx[j] = obstacles[j * 3];
        oby[j] = obstacles[j * 3 + 1];
        float rr = obstacles[j * 3 + 2];
        obr2[j] = rr * rr;
    }

    const float4* b2v = (const float4*)b2s;
    const int ntiles = (nB + 15) >> 4;

    for (int tile = wid; tile < ntiles; tile += nwaves) {
        const int base = tile << 4;

        // x row: only lanes 0..15 need it (one row per lane).
        float xr[5] = {0.f, 0.f, 0.f, 0.f, 0.f};
        if (h16) {
            int row = base + lane; if (row >= nB) row = nB - 1;
            const float* xp = x + (size_t)row * 5;
            #pragma unroll
            for (int c = 0; c < 5; ++c) xr[c] = xp[c];
        }

        // x B-fragment: q=0 lanes hold k=0..5 = {x0..x4, 1.0}; others zero.
        short8v xf;
        {
            float one = h16 ? 1.0f : 0.0f;
            uint4 xv;
            xv.x = pk_bf16(xr[0], xr[1]);
            xv.y = pk_bf16(xr[2], xr[3]);
            xv.z = pk_bf16(xr[4], one);
            xv.w = 0u;
            xf = as_s8(xv);
        }

        // ---- layer 1: 8 MFMA, W1-frags streamed from LDS in pairs;
        // relu+pack immediately (af[ks] <- hacc[2ks], hacc[2ks+1]). ----
        short8v af[4];
        #pragma unroll
        for (int ks = 0; ks < 4; ++ks) {
            f32x4 z = {0.f, 0.f, 0.f, 0.f};
            short8v wA0 = as_s8(w1frag[(2 * ks) * 64 + lane]);
            short8v wA1 = as_s8(w1frag[(2 * ks + 1) * 64 + lane]);
            f32x4 h0 = __builtin_amdgcn_mfma_f32_16x16x32_bf16(wA0, xf, z, 0, 0, 0);
            f32x4 h1 = __builtin_amdgcn_mfma_f32_16x16x32_bf16(wA1, xf, z, 0, 0, 0);
            uint4 v;
            v.x = pk_bf16(fmaxf(h0[0], 0.f), fmaxf(h0[1], 0.f));
            v.y = pk_bf16(fmaxf(h0[2], 0.f), fmaxf(h0[3], 0.f));
            v.z = pk_bf16(fmaxf(h1[0], 0.f), fmaxf(h1[1], 0.f));
            v.w = pk_bf16(fmaxf(h1[2], 0.f), fmaxf(h1[3], 0.f));
            af[ks] = as_s8(v);
        }

        // ---- layer 2: bias-initialized accumulators (LDS broadcast reads) ----
        f32x4 a21a = as_f4(b2v[q]);
        f32x4 a21b = as_f4(b2v[4 + q]);
        f32x4 a22a = as_f4(b2v[8 + q]);
        f32x4 a22b = as_f4(b2v[12 + q]);
        #pragma unroll
        for (int ks = 0; ks < 4; ++ks) {
            a21a = __builtin_amdgcn_mfma_f32_16x16x32_bf16(bfr[     ks], af[ks], a21a, 0, 0, 0);
            a21b = __builtin_amdgcn_mfma_f32_16x16x32_bf16(bfr[ 4 + ks], af[ks], a21b, 0, 0, 0);
            a22a = __builtin_amdgcn_mfma_f32_16x16x32_bf16(bfr[ 8 + ks], af[ks], a22a, 0, 0, 0);
            a22b = __builtin_amdgcn_mfma_f32_16x16x32_bf16(bfr[12 + ks], af[ks], a22b, 0, 0, 0);
        }

        // ---- heads via 2 MFMA: relu'd x21/x22 are already this lane's
        // head-B-fragment (sigma chosen so u=4q+j / 16+4q+(j-4)). ----
        uint4 hv1, hv2;
        hv1.x = pk_bf16(fmaxf(a21a[0], 0.f), fmaxf(a21a[1], 0.f));
        hv1.y = pk_bf16(fmaxf(a21a[2], 0.f), fmaxf(a21a[3], 0.f));
        hv1.z = pk_bf16(fmaxf(a21b[0], 0.f), fmaxf(a21b[1], 0.f));
        hv1.w = pk_bf16(fmaxf(a21b[2], 0.f), fmaxf(a21b[3], 0.f));
        hv2.x = pk_bf16(fmaxf(a22a[0], 0.f), fmaxf(a22a[1], 0.f));
        hv2.y = pk_bf16(fmaxf(a22a[2], 0.f), fmaxf(a22a[3], 0.f));
        hv2.z = pk_bf16(fmaxf(a22b[0], 0.f), fmaxf(a22b[1], 0.f));
        hv2.w = pk_bf16(fmaxf(a22b[2], 0.f), fmaxf(a22b[3], 0.f));

        f32x4 hd;
        hd[0] = h16 ? hb0 : 0.f;
        hd[1] = h16 ? hb1 : 0.f;
        hd[2] = h16 ? hb2 : 0.f;
        hd[3] = h16 ? hb3 : 0.f;
        hd = __builtin_amdgcn_mfma_f32_16x16x32_bf16(hA0, as_s8(hv1), hd, 0, 0, 0);
        hd = __builtin_amdgcn_mfma_f32_16x16x32_bf16(hA1, as_s8(hv2), hd, 0, 0, 0);

        // ---- epilogue: lanes 0..15 own rows base..base+15, heads in hd ----
        if (h16) {
            float x31_0 = hd[0], x31_1 = hd[1], t32_0 = hd[2], t32_1 = hd[3];

            float s0v = __fdividef(4.f, 1.f + __expf(-t32_0));
            float s1v = __fdividef(4.f, 1.f + __expf(-t32_1));
            float hcoef = s0v * s1v;

            float xo[5];
            #pragma unroll
            for (int c = 0; c < 5; ++c) xo[c] = fmaf(xr[c], s2[c], ms[c]);
            float px = xo[0], py = xo[1], th = xo[2], oppx = xo[3], oppy = xo[4];
            float st, ct;
            __sincosf(th, &st, &ct);

            float upper = INFINITY, lower = -INFINITY;
            #pragma unroll
            for (int j = 0; j < 9; ++j) {
                float ox  = (j < 8) ? obx[j]  : oppx;
                float oy  = (j < 8) ? oby[j]  : oppy;
                float rr2 = (j < 8) ? obr2[j] : (0.3f * 0.3f);
                float dx = px - ox, dy = py - oy;
                float bar = fmaf(dx, dx, fmaf(dy, dy, -rr2));
                float g1  = -2.f * fmaf(dx, ct, dy * st);
                float ratio = __fdividef(hcoef * bar, (g1 != 0.f) ? g1 : 1.f);
                if (g1 > 0.f) upper = fminf(upper, ratio);
                if (g1 < 0.f) lower = fmaxf(lower, ratio);
            }
            float u1 = fminf(fmaxf(-x31_0, lower), upper);
            float u2 = -x31_1;

            int row = base + lane;
            if (row < nB) {
                float2 o; o.x = u1; o.y = u2;
                *reinterpret_cast<float2*>(out + 2 * (size_t)row) = o;
            }
        }
    }
}

extern "C" void kernel_launch(void* const* d_in, const int* in_sizes, int n_in,
                              void* d_out, int out_size, void* d_ws, size_t ws_size,
                              hipStream_t stream) {
    const float* x         = (const float*)d_in[0];
    const float* meanp     = (const float*)d_in[1];
    const float* stdp      = (const float*)d_in[2];
    const float* W1        = (const float*)d_in[3];
    const float* b1        = (const float*)d_in[4];
    const float* W21       = (const float*)d_in[5];
    const float* b21       = (const float*)d_in[6];
    const float* W22       = (const float*)d_in[7];
    const float* b22       = (const float*)d_in[8];
    const float* W31       = (const float*)d_in[9];
    const float* b31       = (const float*)d_in[10];
    const float* W32       = (const float*)d_in[11];
    const float* b32       = (const float*)d_in[12];
    const float* obstacles = (const float*)d_in[13];
    float* out = (float*)d_out;

    int nB = in_sizes[0] / 5;
    bnet<<<GRID, BLOCK, 0, stream>>>(
        x, meanp, stdp, W1, b1, W21, b21, W22, b22,
        W31, b31, W32, b32, obstacles, out, nB);
}

// Round 7
// 21.831 us; speedup vs baseline: 1.2550x; 1.2426x over previous
//
#include <hip/hip_runtime.h>
#include <math.h>

typedef __attribute__((ext_vector_type(8))) short short8v;
typedef __attribute__((ext_vector_type(4))) float f32x4;

#define BLOCK 256
#define WPB   4
#define GRID  1024

__device__ inline unsigned int pk_bf16(float lo, float hi) {
    unsigned int r;
    asm("v_cvt_pk_bf16_f32 %0, %1, %2" : "=v"(r) : "v"(lo), "v"(hi));
    return r;
}
__device__ inline short8v as_s8(uint4 v) { union { uint4 u; short8v s; } c; c.u = v; return c.s; }

__global__ __launch_bounds__(BLOCK, 2) void bnet(
    const float* __restrict__ x,
    const float* __restrict__ meanp, const float* __restrict__ stdp,
    const float* __restrict__ W1,  const float* __restrict__ b1,
    const float* __restrict__ W21, const float* __restrict__ b21,
    const float* __restrict__ W22, const float* __restrict__ b22,
    const float* __restrict__ W31, const float* __restrict__ b31,
    const float* __restrict__ W32, const float* __restrict__ b32,
    const float* __restrict__ obstacles,
    float* __restrict__ out, int nB)
{
    // Layer-1 A-frags: [g*64+lane]; lanes<16 hold W1 row 16g+m (k=0..4 w, k=5 b1).
    __shared__ uint4 w1frag[8 * 64];                  // 8 KB
    // Layer-2 A-frags with pi-permuted K (verified rounds 4/6).
    __shared__ uint4 fragB[16 * 64];                  // 16 KB
    __shared__ float obl[32];                         // obx[8] | oby[8] | obr2[8]

    const int t = threadIdx.x;

    {   // zero w1frag (lanes >=16 must be zero)
        uint4 z = {0u, 0u, 0u, 0u};
        w1frag[t] = z; w1frag[t + 256] = z;
    }
    __syncthreads();
    if (t < 128) {   // W1 fragments
        int m = t & 15, g = t >> 4;
        int u = 16 * g + m;
        const float* wr = W1 + u * 5;
        uint4 v;
        v.x = pk_bf16(wr[0], wr[1]);
        v.y = pk_bf16(wr[2], wr[3]);
        v.z = pk_bf16(wr[4], b1[u]);
        v.w = 0u;
        w1frag[g * 64 + m] = v;
    }
    if (t < 8) {
        obl[t]      = obstacles[t * 3];
        obl[8 + t]  = obstacles[t * 3 + 1];
        float rr    = obstacles[t * 3 + 2];
        obl[16 + t] = rr * rr;
    }
    {   // layer-2 fragments (identical mapping to round 4 - verified)
        const float4* w21v = (const float4*)W21;
        const float4* w22v = (const float4*)W22;
        #pragma unroll
        for (int e = 0; e < 4; ++e) {
            int g4   = t + e * 256;
            int uo   = g4 >> 5;
            int h0   = (g4 & 31) << 2;
            int ks   = h0 >> 5;
            int jh   = (h0 >> 4) & 1;
            int qq   = (h0 >> 2) & 3;
            int ln   = (qq << 4) | (uo & 15);
            int half = uo >> 4;
            float4 f1 = w21v[g4];
            float4 f2 = w22v[g4];
            unsigned int* dA = (unsigned int*)&fragB[(half * 4 + ks) * 64 + ln];
            unsigned int* dB = (unsigned int*)&fragB[(8 + half * 4 + ks) * 64 + ln];
            dA[jh * 2] = pk_bf16(f1.x, f1.y); dA[jh * 2 + 1] = pk_bf16(f1.z, f1.w);
            dB[jh * 2] = pk_bf16(f2.x, f2.y); dB[jh * 2 + 1] = pk_bf16(f2.z, f2.w);
        }
    }
    __syncthreads();

    const int lane = t & 63;
    const int q    = lane >> 4;
    const int r15  = lane & 15;
    const bool q0  = (q == 0);
    const int wid    = blockIdx.x * WPB + (t >> 6);
    const int nwaves = GRID * WPB;

    // Resident W2 fragments (64 VGPR).
    short8v bfr[16];
    #pragma unroll
    for (int i = 0; i < 16; ++i) bfr[i] = as_s8(fragB[i * 64 + lane]);

    // Per-lane layer-2 biases and head coefficients (units 4q+r / 16+4q+r).
    float bi21[8], bi22[8];
    float c31_0[8], c31_1[8], c32_0[8], c32_1[8];
    {
        const int o = 4 * q;
        *(float4*)&bi21[0]  = *(const float4*)(b21 + o);
        *(float4*)&bi21[4]  = *(const float4*)(b21 + 16 + o);
        *(float4*)&bi22[0]  = *(const float4*)(b22 + o);
        *(float4*)&bi22[4]  = *(const float4*)(b22 + 16 + o);
        *(float4*)&c31_0[0] = *(const float4*)(W31 + o);
        *(float4*)&c31_0[4] = *(const float4*)(W31 + 16 + o);
        *(float4*)&c31_1[0] = *(const float4*)(W31 + 32 + o);
        *(float4*)&c31_1[4] = *(const float4*)(W31 + 48 + o);
        *(float4*)&c32_0[0] = *(const float4*)(W32 + o);
        *(float4*)&c32_0[4] = *(const float4*)(W32 + 16 + o);
        *(float4*)&c32_1[0] = *(const float4*)(W32 + 32 + o);
        *(float4*)&c32_1[4] = *(const float4*)(W32 + 48 + o);
    }
    const float b31_0 = b31[0], b31_1 = b31[1];
    const float b32_0 = b32[0], b32_1 = b32[1];

    // xo = (x*std+mean)*std+mean = x*std^2 + (mean*std+mean)
    float s2[5], ms[5];
    #pragma unroll
    for (int c = 0; c < 5; ++c) { float m = meanp[c], s = stdp[c]; s2[c] = s * s; ms[c] = fmaf(m, s, m); }

    const int ntiles = (nB + 15) >> 4;
    const int npairs = (ntiles + 1) >> 1;

    int pair = wid;
    if (pair >= npairs) return;

    float xrA[5], xrB[5];
    {
        int rA = pair * 32 + r15;      if (rA >= nB) rA = nB - 1;
        int rB = pair * 32 + 16 + r15; if (rB >= nB) rB = nB - 1;
        const float* pA = x + (size_t)rA * 5;
        const float* pB = x + (size_t)rB * 5;
        #pragma unroll
        for (int c = 0; c < 5; ++c) { xrA[c] = pA[c]; xrB[c] = pB[c]; }
    }

    while (true) {
        const int nxt = pair + nwaves;
        const bool has = nxt < npairs;
        float xA2[5], xB2[5];
        if (has) {   // prefetch next pair
            int rA = nxt * 32 + r15;      if (rA >= nB) rA = nB - 1;
            int rB = nxt * 32 + 16 + r15; if (rB >= nB) rB = nB - 1;
            const float* pA = x + (size_t)rA * 5;
            const float* pB = x + (size_t)rB * 5;
            #pragma unroll
            for (int c = 0; c < 5; ++c) { xA2[c] = pA[c]; xB2[c] = pB[c]; }
        }
        const int baseA = pair * 32;

        // ---- x B-fragments (q=0 lanes: k=0..5 = {x,1.0}) ----
        short8v xfA, xfB;
        {
            float one = q0 ? 1.0f : 0.0f;
            uint4 va, vb;
            va.x = pk_bf16(q0 ? xrA[0] : 0.f, q0 ? xrA[1] : 0.f);
            va.y = pk_bf16(q0 ? xrA[2] : 0.f, q0 ? xrA[3] : 0.f);
            va.z = pk_bf16(q0 ? xrA[4] : 0.f, one);
            va.w = 0u;
            vb.x = pk_bf16(q0 ? xrB[0] : 0.f, q0 ? xrB[1] : 0.f);
            vb.y = pk_bf16(q0 ? xrB[2] : 0.f, q0 ? xrB[3] : 0.f);
            vb.z = pk_bf16(q0 ? xrB[4] : 0.f, one);
            vb.w = 0u;
            xfA = as_s8(va); xfB = as_s8(vb);
        }

        // ---- layer 1: 16 MFMA (2 chains interleaved), relu+pack fused ----
        short8v afA[4], afB[4];
        #pragma unroll
        for (int ks = 0; ks < 4; ++ks) {
            f32x4 z = {0.f, 0.f, 0.f, 0.f};
            short8v w0 = as_s8(w1frag[(2 * ks) * 64 + lane]);
            short8v w1v = as_s8(w1frag[(2 * ks + 1) * 64 + lane]);
            f32x4 hA0 = __builtin_amdgcn_mfma_f32_16x16x32_bf16(w0,  xfA, z, 0, 0, 0);
            f32x4 hA1 = __builtin_amdgcn_mfma_f32_16x16x32_bf16(w1v, xfA, z, 0, 0, 0);
            f32x4 hB0 = __builtin_amdgcn_mfma_f32_16x16x32_bf16(w0,  xfB, z, 0, 0, 0);
            f32x4 hB1 = __builtin_amdgcn_mfma_f32_16x16x32_bf16(w1v, xfB, z, 0, 0, 0);
            uint4 va, vb;
            va.x = pk_bf16(fmaxf(hA0[0], 0.f), fmaxf(hA0[1], 0.f));
            va.y = pk_bf16(fmaxf(hA0[2], 0.f), fmaxf(hA0[3], 0.f));
            va.z = pk_bf16(fmaxf(hA1[0], 0.f), fmaxf(hA1[1], 0.f));
            va.w = pk_bf16(fmaxf(hA1[2], 0.f), fmaxf(hA1[3], 0.f));
            vb.x = pk_bf16(fmaxf(hB0[0], 0.f), fmaxf(hB0[1], 0.f));
            vb.y = pk_bf16(fmaxf(hB0[2], 0.f), fmaxf(hB0[3], 0.f));
            vb.z = pk_bf16(fmaxf(hB1[0], 0.f), fmaxf(hB1[1], 0.f));
            vb.w = pk_bf16(fmaxf(hB1[2], 0.f), fmaxf(hB1[3], 0.f));
            afA[ks] = as_s8(va); afB[ks] = as_s8(vb);
        }

        // ---- layer 2: 32 MFMA in 8 independent acc chains ----
        f32x4 a21aA = {bi21[0], bi21[1], bi21[2], bi21[3]};
        f32x4 a21bA = {bi21[4], bi21[5], bi21[6], bi21[7]};
        f32x4 a22aA = {bi22[0], bi22[1], bi22[2], bi22[3]};
        f32x4 a22bA = {bi22[4], bi22[5], bi22[6], bi22[7]};
        f32x4 a21aB = a21aA, a21bB = a21bA, a22aB = a22aA, a22bB = a22bA;
        #pragma unroll
        for (int ks = 0; ks < 4; ++ks) {
            a21aA = __builtin_amdgcn_mfma_f32_16x16x32_bf16(bfr[     ks], afA[ks], a21aA, 0, 0, 0);
            a21aB = __builtin_amdgcn_mfma_f32_16x16x32_bf16(bfr[     ks], afB[ks], a21aB, 0, 0, 0);
            a21bA = __builtin_amdgcn_mfma_f32_16x16x32_bf16(bfr[ 4 + ks], afA[ks], a21bA, 0, 0, 0);
            a21bB = __builtin_amdgcn_mfma_f32_16x16x32_bf16(bfr[ 4 + ks], afB[ks], a21bB, 0, 0, 0);
            a22aA = __builtin_amdgcn_mfma_f32_16x16x32_bf16(bfr[ 8 + ks], afA[ks], a22aA, 0, 0, 0);
            a22aB = __builtin_amdgcn_mfma_f32_16x16x32_bf16(bfr[ 8 + ks], afB[ks], a22aB, 0, 0, 0);
            a22bA = __builtin_amdgcn_mfma_f32_16x16x32_bf16(bfr[12 + ks], afA[ks], a22bA, 0, 0, 0);
            a22bB = __builtin_amdgcn_mfma_f32_16x16x32_bf16(bfr[12 + ks], afB[ks], a22bB, 0, 0, 0);
        }

        // ---- heads: per-lane partial dots, 2-round shfl reduce, both chains ----
        float p0A = 0.f, p1A = 0.f, p2A = 0.f, p3A = 0.f;
        float p0B = 0.f, p1B = 0.f, p2B = 0.f, p3B = 0.f;
        #pragma unroll
        for (int r = 0; r < 4; ++r) {
            float vA21a = fmaxf(a21aA[r], 0.f), vA21b = fmaxf(a21bA[r], 0.f);
            float vA22a = fmaxf(a22aA[r], 0.f), vA22b = fmaxf(a22bA[r], 0.f);
            float vB21a = fmaxf(a21aB[r], 0.f), vB21b = fmaxf(a21bB[r], 0.f);
            float vB22a = fmaxf(a22aB[r], 0.f), vB22b = fmaxf(a22bB[r], 0.f);
            p0A = fmaf(vA21a, c31_0[r], fmaf(vA21b, c31_0[4 + r], p0A));
            p1A = fmaf(vA21a, c31_1[r], fmaf(vA21b, c31_1[4 + r], p1A));
            p2A = fmaf(vA22a, c32_0[r], fmaf(vA22b, c32_0[4 + r], p2A));
            p3A = fmaf(vA22a, c32_1[r], fmaf(vA22b, c32_1[4 + r], p3A));
            p0B = fmaf(vB21a, c31_0[r], fmaf(vB21b, c31_0[4 + r], p0B));
            p1B = fmaf(vB21a, c31_1[r], fmaf(vB21b, c31_1[4 + r], p1B));
            p2B = fmaf(vB22a, c32_0[r], fmaf(vB22b, c32_0[4 + r], p2B));
            p3B = fmaf(vB22a, c32_1[r], fmaf(vB22b, c32_1[4 + r], p3B));
        }
        p0A += __shfl_xor(p0A, 16); p0A += __shfl_xor(p0A, 32);
        p1A += __shfl_xor(p1A, 16); p1A += __shfl_xor(p1A, 32);
        p2A += __shfl_xor(p2A, 16); p2A += __shfl_xor(p2A, 32);
        p3A += __shfl_xor(p3A, 16); p3A += __shfl_xor(p3A, 32);
        p0B += __shfl_xor(p0B, 16); p0B += __shfl_xor(p0B, 32);
        p1B += __shfl_xor(p1B, 16); p1B += __shfl_xor(p1B, 32);
        p2B += __shfl_xor(p2B, 16); p2B += __shfl_xor(p2B, 32);
        p3B += __shfl_xor(p3B, 16); p3B += __shfl_xor(p3B, 32);

        // ---- epilogue: lanes 0..31 own rows baseA..baseA+31 (2x redundancy gone) ----
        if (lane < 32) {
            const bool sa = (lane < 16);
            float x31_0 = (sa ? p0A : p0B) + b31_0;
            float x31_1 = (sa ? p1A : p1B) + b31_1;
            float t32_0 = (sa ? p2A : p2B) + b32_0;
            float t32_1 = (sa ? p3A : p3B) + b32_1;

            float s0v = __fdividef(4.f, 1.f + __expf(-t32_0));
            float s1v = __fdividef(4.f, 1.f + __expf(-t32_1));
            float hcoef = s0v * s1v;

            float xo[5];
            #pragma unroll
            for (int c = 0; c < 5; ++c) {
                float xc = sa ? xrA[c] : xrB[c];
                xo[c] = fmaf(xc, s2[c], ms[c]);
            }
            float px = xo[0], py = xo[1], th = xo[2], oppx = xo[3], oppy = xo[4];
            float st, ct;
            __sincosf(th, &st, &ct);

            float upper = INFINITY, lower = -INFINITY;
            #pragma unroll
            for (int j = 0; j < 9; ++j) {
                float ox  = (j < 8) ? obl[j]      : oppx;
                float oy  = (j < 8) ? obl[8 + j]  : oppy;
                float rr2 = (j < 8) ? obl[16 + j] : (0.3f * 0.3f);
                float dx = px - ox, dy = py - oy;
                float bar = fmaf(dx, dx, fmaf(dy, dy, -rr2));
                float g1  = -2.f * fmaf(dx, ct, dy * st);
                float ratio = __fdividef(hcoef * bar, (g1 != 0.f) ? g1 : 1.f);
                if (g1 > 0.f) upper = fminf(upper, ratio);
                if (g1 < 0.f) lower = fmaxf(lower, ratio);
            }
            float u1 = fminf(fmaxf(-x31_0, lower), upper);
            float u2 = -x31_1;

            int row = baseA + lane;
            if (row < nB) {
                float2 o; o.x = u1; o.y = u2;
                *reinterpret_cast<float2*>(out + 2 * (size_t)row) = o;
            }
        }

        if (!has) break;
        pair = nxt;
        #pragma unroll
        for (int c = 0; c < 5; ++c) { xrA[c] = xA2[c]; xrB[c] = xB2[c]; }
    }
}

extern "C" void kernel_launch(void* const* d_in, const int* in_sizes, int n_in,
                              void* d_out, int out_size, void* d_ws, size_t ws_size,
                              hipStream_t stream) {
    const float* x         = (const float*)d_in[0];
    const float* meanp     = (const float*)d_in[1];
    const float* stdp      = (const float*)d_in[2];
    const float* W1        = (const float*)d_in[3];
    const float* b1        = (const float*)d_in[4];
    const float* W21       = (const float*)d_in[5];
    const float* b21       = (const float*)d_in[6];
    const float* W22       = (const float*)d_in[7];
    const float* b22       = (const float*)d_in[8];
    const float* W31       = (const float*)d_in[9];
    const float* b31       = (const float*)d_in[10];
    const float* W32       = (const float*)d_in[11];
    const float* b32       = (const float*)d_in[12];
    const float* obstacles = (const float*)d_in[13];
    float* out = (float*)d_out;

    int nB = in_sizes[0] / 5;
    bnet<<<GRID, BLOCK, 0, stream>>>(
        x, meanp, stdp, W1, b1, W21, b21, W22, b22,
        W31, b31, W32, b32, obstacles, out, nB);
}